// Round 8
// baseline (420.314 us; speedup 1.0000x reference)
//
#include <hip/hip_runtime.h>

// spectralAgg R8: barrier-free streaming. One WG (512 thr, 8 waves) per patch.
// Each wave owns an i-slice (8 patch rows = 512 i) and computes a FULL 64x64
// partial Gram over its slice using only its own private LDS region -> the
// load->cvt->LDS->MFMA pipeline has NO cross-wave barriers (anti-convoy).
// E = sum_w (G_w + S_w) + (sum_w S_w)^T  (split-bf16: hi*hi^T + hi*lo^T sym),
// A = softmax(-E) rows (min-stabilized, gamma folded), out = A p (bf16 MFMA),
// phase 3 also i-partitioned per wave (private transpose tile, no barriers).

#define NW  512
#define HWs 262144

typedef __attribute__((ext_vector_type(4)))  __bf16 bf4;
typedef __attribute__((ext_vector_type(8)))  __bf16 bf8;
typedef __attribute__((ext_vector_type(16))) float  f32x16;

#define MFMA __builtin_amdgcn_mfma_f32_32x32x16_bf16

extern "C" __global__ __launch_bounds__(512, 2)
void spectralAgg_kernel(const float* __restrict__ x, const float* __restrict__ g,
                        float* __restrict__ out) {
  // LDS map:
  //  [0, 81920)      per-wave private stage, wave w at w*10240:
  //                    phase1: hi [64 c][80B stride], lo at +5120 [64 c][80B]
  //                    phase3: pT [32 i][144B stride] (4608B)
  //  [0, 16384)      E_lds f32[64][64]   (overlay, after phase-1 barrier)
  //  [16384, 32768)  S_lds f32[64][64]   (overlay)
  //  [81920, 90112)  sA attn bf16 [64 c][128B], XOR swizzled
  __shared__ char lds[90112];
  char*  sStage = lds;
  float* E_lds  = (float*)lds;
  float* S_lds  = (float*)(lds + 16384);
  char*  sA     = lds + 81920;

  const int T   = threadIdx.x;
  const int wv8 = T >> 6;
  const int l   = T & 63;
  const int l31 = l & 31;
  const int hh  = l >> 5;
  const int cl  = l >> 3;          // lane's base channel sub-index (0..7)
  const int il  = (l & 7) * 4;     // lane's i-offset within a 32-col subtile

  const int wg = blockIdx.x;       // 512 = 8 batches * 64 patches (identity map)
  const int b  = wg >> 6;
  const int pp = wg & 63;
  const int pr = pp >> 3, pc = pp & 7;
  const size_t pbase = (size_t)b * 64 * HWs + (size_t)(pr * 64) * NW + (size_t)(pc * 64);
  const float* xp = x + pbase;
  float* op = out + pbase;

  char* myStage = sStage + wv8 * 10240;
  char* myHi = myStage;
  char* myLo = myStage + 5120;

  // subtile st (0..15): patch row r = wv8*8 + (st>>1), col half ch = (st&1)*32
  // lane loads 8 float4: channel c = cl + 8j, 4 consecutive i at il.
#define LOADST(stv, R)                                                          \
  {                                                                             \
    const int r_ = wv8 * 8 + ((stv) >> 1);                                      \
    const int ch_ = ((stv) & 1) * 32;                                           \
    const float* base_ = xp + (size_t)r_ * NW + ch_ + il;                       \
    _Pragma("unroll")                                                           \
    for (int j = 0; j < 8; ++j)                                                 \
      R[j] = *(const float4*)(base_ + (size_t)(cl + 8 * j) * HWs);              \
  }

  // ================= Phase 1: per-wave partial Gram, NO barriers ============
  f32x16 G00, G01, G10, G11, S00, S01, S10, S11;
#pragma unroll
  for (int i = 0; i < 16; ++i) {
    G00[i]=0.f; G01[i]=0.f; G10[i]=0.f; G11[i]=0.f;
    S00[i]=0.f; S01[i]=0.f; S10[i]=0.f; S11[i]=0.f;
  }

  float4 rA[8], rB[8];
  LOADST(0, rA);

  for (int st = 0; st < 16; ++st) {
    if (st + 1 < 16) LOADST(st + 1, rB);        // in flight across whole body
    // cvt + stage hi/lo into private region
#pragma unroll
    for (int j = 0; j < 8; ++j) {
      const int c = cl + 8 * j;
      const float4 v = rA[j];
      bf4 h, lo;
      h[0]=(__bf16)v.x; h[1]=(__bf16)v.y; h[2]=(__bf16)v.z; h[3]=(__bf16)v.w;
      lo[0]=(__bf16)(v.x-(float)h[0]); lo[1]=(__bf16)(v.y-(float)h[1]);
      lo[2]=(__bf16)(v.z-(float)h[2]); lo[3]=(__bf16)(v.w-(float)h[3]);
      *(bf4*)(myHi + c * 80 + il * 2) = h;
      *(bf4*)(myLo + c * 80 + il * 2) = lo;
    }
    // MFMA over the 32-i subtile (2 k-steps); compiler inserts lgkm waits
#pragma unroll
    for (int kk = 0; kk < 2; ++kk) {
      const int ko = kk * 32 + hh * 16;
      const bf8 a0 = *(const bf8*)(myHi + (size_t)l31 * 80 + ko);
      const bf8 a1 = *(const bf8*)(myHi + (size_t)(32 + l31) * 80 + ko);
      const bf8 q0 = *(const bf8*)(myLo + (size_t)l31 * 80 + ko);
      const bf8 q1 = *(const bf8*)(myLo + (size_t)(32 + l31) * 80 + ko);
      G00 = MFMA(a0, a0, G00, 0, 0, 0);
      G01 = MFMA(a0, a1, G01, 0, 0, 0);
      G10 = MFMA(a1, a0, G10, 0, 0, 0);
      G11 = MFMA(a1, a1, G11, 0, 0, 0);
      S00 = MFMA(a0, q0, S00, 0, 0, 0);
      S01 = MFMA(a0, q1, S01, 0, 0, 0);
      S10 = MFMA(a1, q0, S10, 0, 0, 0);
      S11 = MFMA(a1, q1, S11, 0, 0, 0);
    }
#pragma unroll
    for (int e = 0; e < 8; ++e) rA[e] = rB[e];
  }

  // ================= one-time reduction: E = sum(G+S) + (sum S)^T ===========
  __syncthreads();
  {  // zero E,S (32KB = 2048 float4)
    float4 z; z.x=0.f; z.y=0.f; z.z=0.f; z.w=0.f;
    float4* pz = (float4*)lds;
#pragma unroll
    for (int k = 0; k < 4; ++k) pz[T * 4 + k] = z;
  }
  __syncthreads();
  for (int rd = 0; rd < 8; ++rd) {             // deterministic round-robin
    if (wv8 == rd) {
#pragma unroll
      for (int i = 0; i < 16; ++i) {
        const int rr = (i & 3) + ((i >> 2) << 3) + (hh << 2);
        E_lds[rr * 64 + l31]             += G00[i] + S00[i];
        E_lds[rr * 64 + 32 + l31]        += G01[i] + S01[i];
        E_lds[(32 + rr) * 64 + l31]      += G10[i] + S10[i];
        E_lds[(32 + rr) * 64 + 32 + l31] += G11[i] + S11[i];
        S_lds[rr * 64 + l31]             += S00[i];
        S_lds[rr * 64 + 32 + l31]        += S01[i];
        S_lds[(32 + rr) * 64 + l31]      += S10[i];
        S_lds[(32 + rr) * 64 + 32 + l31] += S11[i];
      }
    }
    __syncthreads();
  }
  {  // E += S^T
    const int c = T >> 3;
#pragma unroll
    for (int k = 0; k < 8; ++k) {
      const int d = (T & 7) * 8 + k;
      E_lds[c * 64 + d] += S_lds[d * 64 + c];
    }
  }
  __syncthreads();

  // ================= softmax(-E) rows -> sA (gamma folded) ==================
  const float gs = 1.0f + g[0];
#pragma unroll 1
  for (int rr2 = 0; rr2 < 8; ++rr2) {
    const int c = wv8 * 8 + rr2;
    const float e = E_lds[c * 64 + l];
    float mn = e;
#pragma unroll
    for (int o = 32; o; o >>= 1) mn = fminf(mn, __shfl_xor(mn, o));
    const float w = __expf(mn - e);
    float s = w;
#pragma unroll
    for (int o = 32; o; o >>= 1) s += __shfl_xor(s, o);
    const float a = gs * w / s;
    *(__bf16*)(sA + c * 128 + ((l * 2) ^ ((c & 7) << 4))) = (__bf16)a;
  }
  __syncthreads();

  // ================= Phase 3: per-wave PV, NO barriers ======================
  // B-fragments (attention rows, stage-invariant) hoisted to registers.
  bf8 bfr[2][4];
#pragma unroll
  for (int c2 = 0; c2 < 2; ++c2)
#pragma unroll
    for (int k0 = 0; k0 < 4; ++k0)
      bfr[c2][k0] = *(const bf8*)(sA + (size_t)(c2 * 32 + l31) * 128 +
                                  ((k0 * 32 + hh * 16) ^ ((l31 & 7) << 4)));

  LOADST(0, rA);
  for (int st = 0; st < 16; ++st) {
    if (st + 1 < 16) LOADST(st + 1, rB);
    // transpose-convert into private pT [32 i][144B]
#pragma unroll
    for (int j = 0; j < 8; ++j) {
      const int c = cl + 8 * j;
      const float4 v = rA[j];
      *(__bf16*)(myStage + (size_t)(il + 0) * 144 + c * 2) = (__bf16)v.x;
      *(__bf16*)(myStage + (size_t)(il + 1) * 144 + c * 2) = (__bf16)v.y;
      *(__bf16*)(myStage + (size_t)(il + 2) * 144 + c * 2) = (__bf16)v.z;
      *(__bf16*)(myStage + (size_t)(il + 3) * 144 + c * 2) = (__bf16)v.w;
    }
    f32x16 o0, o1;
#pragma unroll
    for (int i = 0; i < 16; ++i) { o0[i] = 0.f; o1[i] = 0.f; }
#pragma unroll
    for (int ks = 0; ks < 4; ++ks) {
      const bf8 pa = *(const bf8*)(myStage + (size_t)l31 * 144 + ks * 32 + hh * 16);
      o0 = MFMA(pa, bfr[0][ks], o0, 0, 0, 0);
      o1 = MFMA(pa, bfr[1][ks], o1, 0, 0, 0);
    }
    {
      const int r  = wv8 * 8 + (st >> 1);
      const int ch = (st & 1) * 32;
#pragma unroll
      for (int rq = 0; rq < 4; ++rq) {
        const int io = rq * 8 + hh * 4;
        float* orow = op + (size_t)r * NW + ch + io;
        float4 q0; q0.x=o0[rq*4+0]; q0.y=o0[rq*4+1]; q0.z=o0[rq*4+2]; q0.w=o0[rq*4+3];
        *(float4*)(orow + (size_t)l31 * HWs) = q0;
        float4 q1; q1.x=o1[rq*4+0]; q1.y=o1[rq*4+1]; q1.z=o1[rq*4+2]; q1.w=o1[rq*4+3];
        *(float4*)(orow + (size_t)(32 + l31) * HWs) = q1;
      }
    }
#pragma unroll
    for (int e = 0; e < 8; ++e) rA[e] = rB[e];
  }
}

extern "C" void kernel_launch(void* const* d_in, const int* in_sizes, int n_in,
                              void* d_out, int out_size, void* d_ws, size_t ws_size,
                              hipStream_t stream) {
  const float* x = (const float*)d_in[0];
  const float* g = (const float*)d_in[1];
  float* o = (float*)d_out;
  spectralAgg_kernel<<<dim3(512), dim3(512), 0, stream>>>(x, g, o);
}

// Round 9
// 410.767 us; speedup vs baseline: 1.0232x; 1.0232x over previous
//
#include <hip/hip_runtime.h>

// spectralAgg R9: 3-kernel pipeline, all heavy HBM streams (near-)sequential.
//  K1: read x (1KB runs), partial Gram per (b,pr,hq,wh) -> Epart[pat][hq] f32,
//      AND pack bf16-hi transposed -> wsHi[pat][i(4096)][c(64)] (x read ONCE).
//  K2: reduce 4 partials + softmax(-E) (min-stabilized, gamma folded) -> A[pat][c][d] bf16.
//  K3: PV out = A p  -- reads wsHi fully sequentially, writes out.
// Split-bf16 Gram: E = hi hi^T + S + S^T, S = hi lo^T (established R2-R8).
// Falls back to proven R4 monolithic kernel if ws_size < ~292MB.

#define NW  512
#define HWs 262144

typedef __attribute__((ext_vector_type(4)))  __bf16 bf4;
typedef __attribute__((ext_vector_type(8)))  __bf16 bf8;
typedef __attribute__((ext_vector_type(16))) float  f32x16;

#define MFMA __builtin_amdgcn_mfma_f32_32x32x16_bf16
#define F4E(v,j) ((j)==0?(v).x:(j)==1?(v).y:(j)==2?(v).z:(v).w)

__device__ __forceinline__ void bar_lgkm() {
  asm volatile("s_waitcnt lgkmcnt(0)" ::: "memory");
  __builtin_amdgcn_s_barrier();
}

// ======================= K1: partial Gram + hi-pack =======================
// grid 512: (b, pr, hq, wh). 512 thr. WG covers 16 rows x 256 w (4 patches) x 64c.
extern "C" __global__ __launch_bounds__(512)
void k1_gram(const float* __restrict__ x, float* __restrict__ ep,
             __bf16* __restrict__ wsHi) {
  __shared__ char lds[66560];        // sHi 32KB + sLo 32KB; overlay S_lds 66.5KB
  char* sHi = lds;                   // [64 c][512 B], XOR-swizzled by c
  char* sLo = lds + 32768;
  float* S_lds = (float*)lds;        // [4 p][64][65] f32 (after K loop)

  const int T   = threadIdx.x;
  const int wv8 = T >> 6;
  const int l   = T & 63;
  const int l31 = l & 31;
  const int hh  = l >> 5;

  const int bid = blockIdx.x;        // b*64 + pr*8 + hq*2 + wh
  const int wh = bid & 1;
  const int hq = (bid >> 1) & 3;
  const int pr = (bid >> 3) & 7;
  const int b  = bid >> 6;

  const int pl = wv8 & 3;            // wave's patch within the half
  const int ct = wv8 >> 2;           // wave's E row-half
  const int pc = wh * 4 + pl;
  const int pat  = b * 64 + pr * 8 + pc;     // this wave's Gram patch
  const int row0 = pr * 64 + hq * 16;        // image row base of band

  // loads: instr j -> channel c = wv8*8+j, full wave covers 256 floats (1KB run)
  const float* xb = x + (size_t)b * 64 * HWs + (size_t)row0 * NW + wh * 256 + l * 4;

  f32x16 G0, G1, S0, S1;
#pragma unroll
  for (int i = 0; i < 16; ++i) { G0[i]=0.f; G1[i]=0.f; S0[i]=0.f; S1[i]=0.f; }

  float4 rA[8], rB[8];
#pragma unroll
  for (int j = 0; j < 8; ++j)
    rA[j] = *(const float4*)(xb + (size_t)(wv8 * 8 + j) * HWs);

  for (int r = 0; r < 16; ++r) {
    if (r + 1 < 16) {
#pragma unroll
      for (int j = 0; j < 8; ++j)
        rB[j] = *(const float4*)(xb + (size_t)(wv8 * 8 + j) * HWs + (size_t)(r + 1) * NW);
    }
    // cvt + stage hi/lo; keep hi bf4s for the transposed pack
    bf4 hA[8];
#pragma unroll
    for (int j = 0; j < 8; ++j) {
      const int c = wv8 * 8 + j;
      const float4 v = rA[j];
      bf4 h, lo;
      h[0]=(__bf16)v.x; h[1]=(__bf16)v.y; h[2]=(__bf16)v.z; h[3]=(__bf16)v.w;
      lo[0]=(__bf16)(v.x-(float)h[0]); lo[1]=(__bf16)(v.y-(float)h[1]);
      lo[2]=(__bf16)(v.z-(float)h[2]); lo[3]=(__bf16)(v.w-(float)h[3]);
      hA[j] = h;
      const int off = c * 512 + ((l * 8) ^ ((c & 31) << 4));
      *(bf4*)(sHi + off) = h;
      *(bf4*)(sLo + off) = lo;
    }
    // pack transposed hi -> wsHi[pat_w][i][c]: thread has 8 consecutive c x 4 w
#pragma unroll
    for (int k2 = 0; k2 < 4; ++k2) {
      bf8 pk;
#pragma unroll
      for (int jj = 0; jj < 8; ++jj) pk[jj] = hA[jj][k2];
      const int wloc256 = l * 4 + k2;            // w within the 256-half
      const int pl_w = wloc256 >> 6;
      const int w_loc = wloc256 & 63;
      const int pat_w = b * 64 + pr * 8 + wh * 4 + pl_w;
      const int i = (hq * 16 + r) * 64 + w_loc;
      *(bf8*)((char*)wsHi + (size_t)pat_w * 524288 + (size_t)i * 128 + wv8 * 16) = pk;
    }
    bar_lgkm();
    // Gram MFMA: wave (pl, ct): E rows ct*32.., all 64 cols, k = patch's 64 w
#pragma unroll
    for (int ks = 0; ks < 4; ++ks) {
      const int kb = pl * 128 + ks * 32 + hh * 16;
      const int ca = ct * 32 + l31;
      const bf8 a   = *(const bf8*)(sHi + ca * 512 + (kb ^ ((ca & 31) << 4)));
      const bf8 bh0 = *(const bf8*)(sHi + l31 * 512 + (kb ^ ((l31 & 31) << 4)));
      const bf8 bh1 = *(const bf8*)(sHi + (32 + l31) * 512 + (kb ^ (((32 + l31) & 31) << 4)));
      const bf8 bl0 = *(const bf8*)(sLo + l31 * 512 + (kb ^ ((l31 & 31) << 4)));
      const bf8 bl1 = *(const bf8*)(sLo + (32 + l31) * 512 + (kb ^ (((32 + l31) & 31) << 4)));
      G0 = MFMA(a, bh0, G0, 0, 0, 0);
      G1 = MFMA(a, bh1, G1, 0, 0, 0);
      S0 = MFMA(a, bl0, S0, 0, 0, 0);
      S1 = MFMA(a, bl1, S1, 0, 0, 0);
    }
    bar_lgkm();
#pragma unroll
    for (int e = 0; e < 8; ++e) rA[e] = rB[e];
  }

  // epilogue: S -> LDS, then Epart = G + S + S^T
#pragma unroll
  for (int i = 0; i < 16; ++i) {
    const int cr = ct * 32 + (i & 3) + ((i >> 2) << 3) + (hh << 2);
    S_lds[pl * 4160 + cr * 65 + l31]      = S0[i];
    S_lds[pl * 4160 + cr * 65 + 32 + l31] = S1[i];
  }
  bar_lgkm();
  float* epb = ep + ((size_t)(pat * 4 + hq) << 12);
#pragma unroll
  for (int i = 0; i < 16; ++i) {
    const int cr = ct * 32 + (i & 3) + ((i >> 2) << 3) + (hh << 2);
    epb[cr * 64 + l31]      = G0[i] + S0[i] + S_lds[pl * 4160 + l31 * 65 + cr];
    epb[cr * 64 + 32 + l31] = G1[i] + S1[i] + S_lds[pl * 4160 + (32 + l31) * 65 + cr];
  }
}

// ======================= K2: reduce + softmax =======================
extern "C" __global__ __launch_bounds__(256)
void k2_softmax(const float* __restrict__ ep, const float* __restrict__ g,
                __bf16* __restrict__ attn) {
  const int pat = blockIdx.x;
  const int w4 = threadIdx.x >> 6, l = threadIdx.x & 63;
  const float gs = 1.0f + g[0];
  const float* e0 = ep + ((size_t)(pat * 4) << 12);
#pragma unroll 1
  for (int cc = 0; cc < 16; ++cc) {
    const int c = w4 * 16 + cc;
    const int o = c * 64 + l;
    const float e = e0[o] + e0[4096 + o] + e0[8192 + o] + e0[12288 + o];
    float mn = e;
#pragma unroll
    for (int off = 32; off; off >>= 1) mn = fminf(mn, __shfl_xor(mn, off));
    const float w = __expf(mn - e);
    float s = w;
#pragma unroll
    for (int off = 32; off; off >>= 1) s += __shfl_xor(s, off);
    attn[(size_t)pat * 4096 + o] = (__bf16)(gs * w / s);
  }
}

// ======================= K3: PV, sequential reads =======================
// grid 256: (b, pr, hq). 512 thr. Per patch p: 4 chunks of 256 i x 64 c.
extern "C" __global__ __launch_bounds__(512)
void k3_pv(const __bf16* __restrict__ wsHi, const __bf16* __restrict__ attn,
           float* __restrict__ out) {
  __shared__ char lds[65536];        // two 32KB halves: [256 i][128B] swizzled
  const int T   = threadIdx.x;
  const int wv8 = T >> 6;
  const int l   = T & 63;
  const int l31 = l & 31;
  const int hh  = l >> 5;

  const int bid = blockIdx.x;        // b*32 + pr*4 + hq
  const int hq = bid & 3;
  const int pr = (bid >> 2) & 7;
  const int b  = bid >> 5;

  const int ii  = T >> 1;            // staging row 0..255
  const int haf = T & 1;

  float4 rS[4], rT[4];
  // prefetch chunk s=0 (p=0, cc=0)
  {
    const size_t src0 = (size_t)(b * 64 + pr * 8) * 524288 + (size_t)(hq * 1024) * 128;
#pragma unroll
    for (int q = 0; q < 4; ++q)
      rS[q] = *(const float4*)((const char*)wsHi + src0 + (size_t)ii * 128 + haf * 64 + q * 16);
  }

  for (int p = 0; p < 8; ++p) {
    const int pat = b * 64 + pr * 8 + p;
    // A-frags (stage-invariant per patch) from global
    bf8 af[2][4];
#pragma unroll
    for (int mt = 0; mt < 2; ++mt)
#pragma unroll
      for (int ks = 0; ks < 4; ++ks)
        af[mt][ks] = *(const bf8*)(attn + (size_t)pat * 4096 +
                                   (mt * 32 + l31) * 64 + ks * 16 + hh * 8);

    for (int cc = 0; cc < 4; ++cc) {
      const int s = p * 4 + cc;
      char* buf = lds + (s & 1) * 32768;
      // write staged regs -> LDS (swizzled)
#pragma unroll
      for (int q = 0; q < 4; ++q) {
        const int off = ii * 128 + (((haf * 64 + q * 16)) ^ ((ii & 7) << 4));
        *(float4*)(buf + off) = rS[q];
      }
      // prefetch next chunk
      if (s + 1 < 32) {
        const int pn = (s + 1) >> 2, cn = (s + 1) & 3;
        const size_t src = (size_t)(b * 64 + pr * 8 + pn) * 524288 +
                           (size_t)(hq * 1024 + cn * 256) * 128;
#pragma unroll
        for (int q = 0; q < 4; ++q)
          rT[q] = *(const float4*)((const char*)wsHi + src + (size_t)ii * 128 + haf * 64 + q * 16);
      }
      bar_lgkm();

      f32x16 o0, o1;
#pragma unroll
      for (int i = 0; i < 16; ++i) { o0[i] = 0.f; o1[i] = 0.f; }
#pragma unroll
      for (int ks = 0; ks < 4; ++ks) {
        const int irow = wv8 * 32 + l31;
        const bf8 pa = *(const bf8*)(buf + irow * 128 +
                                     (((ks * 32 + hh * 16)) ^ ((irow & 7) << 4)));
        o0 = MFMA(pa, af[0][ks], o0, 0, 0, 0);
        o1 = MFMA(pa, af[1][ks], o1, 0, 0, 0);
      }
      // stores: lane -> c, regs -> i
      const int i_base = hq * 1024 + cc * 256 + wv8 * 32;
#pragma unroll
      for (int rq = 0; rq < 4; ++rq) {
        const int ig = i_base + rq * 8 + hh * 4;
        const int rl = ig >> 6, wl = ig & 63;
        float* orow = out + (size_t)b * 64 * HWs + (size_t)(pr * 64 + rl) * NW + p * 64 + wl;
        float4 q0; q0.x=o0[rq*4+0]; q0.y=o0[rq*4+1]; q0.z=o0[rq*4+2]; q0.w=o0[rq*4+3];
        *(float4*)(orow + (size_t)l31 * HWs) = q0;
        float4 q1; q1.x=o1[rq*4+0]; q1.y=o1[rq*4+1]; q1.z=o1[rq*4+2]; q1.w=o1[rq*4+3];
        *(float4*)(orow + (size_t)(32 + l31) * HWs) = q1;
      }
      bar_lgkm();
#pragma unroll
      for (int e = 0; e < 4; ++e) rS[e] = rT[e];
    }
  }
}

// ======================= fallback: R4 monolithic (proven) =======================
#define NS1 16
#define NS3 16
__device__ __forceinline__ void fb_load1(const float* g1, int st, float4 (&R)[16]) {
  const float* gp = g1 + (size_t)st * 4 * NW;
#pragma unroll
  for (int rl = 0; rl < 4; ++rl)
#pragma unroll
    for (int j = 0; j < 4; ++j)
      R[rl * 4 + j] = *(const float4*)(gp + (size_t)rl * NW + j * 4);
}
__device__ __forceinline__ void fb_cvtw1(char* wH, char* wL, int q_ld, int swzw,
                                         const float4 (&R)[16]) {
#pragma unroll
  for (int rl = 0; rl < 4; ++rl)
#pragma unroll
    for (int s = 0; s < 2; ++s) {
      const float4 va = R[rl * 4 + s * 2], vb = R[rl * 4 + s * 2 + 1];
      const float f[8] = {va.x, va.y, va.z, va.w, vb.x, vb.y, vb.z, vb.w};
      bf8 h, lo;
#pragma unroll
      for (int e = 0; e < 8; ++e) { h[e] = (__bf16)f[e]; lo[e] = (__bf16)(f[e] - (float)h[e]); }
      const int boff = (rl * 128 + q_ld * 32 + s * 16) ^ swzw;
      *(bf8*)(wH + boff) = h;
      *(bf8*)(wL + boff) = lo;
    }
}
__device__ __forceinline__ void fb_load3(const float* g3, int st, float4 (&R)[16]) {
  const float* gp = g3 + (size_t)st * 4 * NW;
#pragma unroll
  for (int cc = 0; cc < 4; ++cc)
#pragma unroll
    for (int j = 0; j < 4; ++j)
      R[cc * 4 + j] = *(const float4*)(gp + (size_t)cc * HWs + j * 4);
}
__device__ __forceinline__ void fb_cvtw3(char* sT, int cg, int iq, const float4 (&R)[16]) {
#pragma unroll
  for (int w = 0; w < 16; ++w) {
    bf4 q;
#pragma unroll
    for (int cc = 0; cc < 4; ++cc) q[cc] = (__bf16)F4E(R[cc * 4 + (w >> 2)], w & 3);
    const int iloc = iq * 16 + w;
    const int sw = ((iloc & 15) ^ ((iloc >> 4) & 7)) << 4;
    const int boff = (iloc & 127) * 256 + ((((iloc >> 7) << 7) + cg * 8) ^ sw);
    *(bf4*)(sT + boff) = q;
  }
}
extern "C" __global__ __launch_bounds__(256, 2)
void spectralAgg_fallback(const float* __restrict__ x, const float* __restrict__ g,
                          float* __restrict__ out) {
  __shared__ char lds[73728];
  char* sH = lds;
  char* sL = lds + 32768;
  char* sA = lds + 65536;
  const int t = threadIdx.x, wv = t >> 6, l = t & 63, l31 = l & 31, hh = l >> 5;
  const int wg = blockIdx.x, b = wg >> 6, pp = wg & 63, pr = pp >> 3, pcq = pp & 7;
  const size_t pbase = (size_t)b*64*HWs + (size_t)(pr*64)*NW + (size_t)(pcq*64);
  const float* xp = x + pbase;
  float* op = out + pbase;
  const int c_ld = t >> 2, q_ld = t & 3;
  const float* g1 = xp + (size_t)c_ld * HWs + q_ld * 16;
  char* wH = sH + c_ld * 512;
  char* wL = sL + c_ld * 512;
  const int swzw = (c_ld & 31) << 4;
  const int ct = wv >> 1, dt = wv & 1;
  const char* pA  = sH + (size_t)(ct*32+l31)*512;
  const char* pBh = sH + (size_t)(dt*32+l31)*512;
  const char* pBl = sL + (size_t)(dt*32+l31)*512;
  const int swzr = l31 << 4;
  f32x16 accG, accS;
#pragma unroll
  for (int i = 0; i < 16; ++i) { accG[i] = 0.f; accS[i] = 0.f; }
  float4 ra[16], rb[16];
  fb_load1(g1, 0, ra);
  for (int st = 0; st < NS1; ++st) {
    fb_load1(g1, (st + 1 < NS1) ? st + 1 : st, rb);
    fb_cvtw1(wH, wL, q_ld, swzw, ra);
    bar_lgkm();
#pragma unroll
    for (int k0 = 0; k0 < 16; ++k0) {
      const int off = (k0 * 32 + hh * 16) ^ swzr;
      const bf8 a  = *(const bf8*)(pA + off);
      const bf8 bh = *(const bf8*)(pBh + off);
      const bf8 bl = *(const bf8*)(pBl + off);
      accG = MFMA(a, bh, accG, 0, 0, 0);
      accS = MFMA(a, bl, accS, 0, 0, 0);
    }
    bar_lgkm();
#pragma unroll
    for (int e = 0; e < 16; ++e) ra[e] = rb[e];
  }
  float* S_lds = (float*)sL;
  float* E_lds = (float*)sH;
#pragma unroll
  for (int i = 0; i < 16; ++i) {
    const int cr = ct*32 + (i&3) + ((i>>2)<<3) + (hh<<2);
    S_lds[cr*64 + dt*32 + l31] = accS[i];
  }
  bar_lgkm();
#pragma unroll
  for (int i = 0; i < 16; ++i) {
    const int cr = ct*32 + (i&3) + ((i>>2)<<3) + (hh<<2);
    const int d = dt*32 + l31;
    E_lds[cr*64 + d] = accG[i] + accS[i] + S_lds[d*64 + cr];
  }
  bar_lgkm();
  const int cg = t >> 4, iq = t & 15;
  const float* g3 = xp + (size_t)(cg*4)*HWs + (size_t)(iq>>2)*NW + (iq&3)*16;
  fb_load3(g3, 0, ra);
  const float gs = 1.0f + g[0];
#pragma unroll 1
  for (int rr = 0; rr < 16; ++rr) {
    const int c = wv*16 + rr;
    const float e = E_lds[c*64 + l];
    float mn = e;
#pragma unroll
    for (int o = 32; o; o >>= 1) mn = fminf(mn, __shfl_xor(mn, o));
    const float w = __expf(mn - e);
    float s = w;
#pragma unroll
    for (int o = 32; o; o >>= 1) s += __shfl_xor(s, o);
    *(__bf16*)(sA + c*128 + ((l*2) ^ ((c&7)<<4))) = (__bf16)(gs * w / s);
  }
  bar_lgkm();
  bf8 bfr[2][4];
#pragma unroll
  for (int c2 = 0; c2 < 2; ++c2)
#pragma unroll
    for (int k0 = 0; k0 < 4; ++k0)
      bfr[c2][k0] = *(const bf8*)(sA + (size_t)(c2*32+l31)*128 +
                                  ((k0*32 + hh*16) ^ ((l31&7)<<4)));
  for (int st = 0; st < NS3; ++st) {
    fb_load3(g3, (st + 1 < NS3) ? st + 1 : st, rb);
    fb_cvtw3(sH, cg, iq, ra);
    bar_lgkm();
    f32x16 oo0[2], oo1[2];
#pragma unroll
    for (int it = 0; it < 2; ++it)
#pragma unroll
      for (int i = 0; i < 16; ++i) { oo0[it][i] = 0.f; oo1[it][i] = 0.f; }
#pragma unroll
    for (int it = 0; it < 2; ++it) {
      const int i = wv*64 + it*32 + l31;
      const char* base = sH + (size_t)(i & 127) * 256;
      const int hb = (i >> 7) * 128;
      const int sw = ((i & 15) ^ ((i >> 4) & 7)) << 4;
#pragma unroll
      for (int k0 = 0; k0 < 4; ++k0) {
        const bf8 pa = *(const bf8*)(base + ((hb + k0*32 + hh*16) ^ sw));
        oo0[it] = MFMA(pa, bfr[0][k0], oo0[it], 0, 0, 0);
        oo1[it] = MFMA(pa, bfr[1][k0], oo1[it], 0, 0, 0);
      }
    }
#pragma unroll
    for (int it = 0; it < 2; ++it)
#pragma unroll
      for (int rq = 0; rq < 4; ++rq) {
        const int iloc = wv*64 + it*32 + rq*8 + hh*4;
        const int gi = st*256 + iloc;
        float* oprow = op + (size_t)(gi >> 6)*NW + (gi & 63);
        float4 q0; q0.x=oo0[it][rq*4+0]; q0.y=oo0[it][rq*4+1]; q0.z=oo0[it][rq*4+2]; q0.w=oo0[it][rq*4+3];
        *(float4*)(oprow + (size_t)l31*HWs) = q0;
        float4 q1; q1.x=oo1[it][rq*4+0]; q1.y=oo1[it][rq*4+1]; q1.z=oo1[it][rq*4+2]; q1.w=oo1[it][rq*4+3];
        *(float4*)(oprow + (size_t)(32+l31)*HWs) = q1;
      }
    bar_lgkm();
#pragma unroll
    for (int e = 0; e < 16; ++e) ra[e] = rb[e];
  }
}

extern "C" void kernel_launch(void* const* d_in, const int* in_sizes, int n_in,
                              void* d_out, int out_size, void* d_ws, size_t ws_size,
                              hipStream_t stream) {
  const float* x = (const float*)d_in[0];
  const float* g = (const float*)d_in[1];
  float* o = (float*)d_out;
  const size_t epB  = (size_t)512 * 4 * 4096 * 4;     // 32 MB
  const size_t aB   = (size_t)512 * 4096 * 2;         // 4 MB
  const size_t hiB  = (size_t)512 * 524288;           // 256 MB
  if (ws_size >= epB + aB + hiB) {
    float*  ep   = (float*)d_ws;
    __bf16* attn = (__bf16*)((char*)d_ws + epB);
    __bf16* wsHi = (__bf16*)((char*)d_ws + epB + aB);
    k1_gram<<<dim3(512), dim3(512), 0, stream>>>(x, ep, wsHi);
    k2_softmax<<<dim3(512), dim3(256), 0, stream>>>(ep, g, attn);
    k3_pv<<<dim3(256), dim3(512), 0, stream>>>(wsHi, attn, o);
  } else {
    spectralAgg_fallback<<<dim3(512), dim3(256), 0, stream>>>(x, g, o);
  }
}